// Round 2
// baseline (495.461 us; speedup 1.0000x reference)
//
#include <hip/hip_runtime.h>
#include <hip/hip_bf16.h>
#include <math.h>

// ---------------------------------------------------------------------------
// UpdateAttn: decoder block = QKV proj -> MHA (no mask) -> Wo + res + LN1
//             -> Wff + res + LN2 -> 2*out + pos_emb(batch)
// S=2048 B=2 D=1024 H=16 DH=64.  All GEMMs bf16 MFMA; residual/LN in f32.
// R1: attention rewritten as 2-pass (exact rowmax, then exp+PV) with swapped
//     QK^T so softmax has NO per-iteration cross-lane ops and no rescaling.
// ---------------------------------------------------------------------------

typedef __bf16 bf16x8 __attribute__((ext_vector_type(8)));
typedef float f32x4  __attribute__((ext_vector_type(4)));

typedef const __attribute__((address_space(1))) unsigned int as1_uint;
typedef __attribute__((address_space(3))) unsigned int as3_uint;

constexpr int S_SEQ = 2048;
constexpr int DM    = 1024;
constexpr int DH    = 64;
constexpr float SM_SCALE = 0.125f;      // 1/sqrt(64)

#define WS_MB (1ull << 20)

__device__ __forceinline__ void gload16(void* lds, const void* g) {
  __builtin_amdgcn_global_load_lds((as1_uint*)g, (as3_uint*)lds, 16, 0, 0);
}

// -------------------------- f32 -> bf16 convert ----------------------------
__global__ void cvt_f32_bf16(const float* __restrict__ in,
                             __hip_bfloat16* __restrict__ out, int n4) {
  int idx = blockIdx.x * blockDim.x + threadIdx.x;
  if (idx >= n4) return;
  float4 v = ((const float4*)in)[idx];
  __hip_bfloat16 tmp[4];
  tmp[0] = __float2bfloat16(v.x);
  tmp[1] = __float2bfloat16(v.y);
  tmp[2] = __float2bfloat16(v.z);
  tmp[3] = __float2bfloat16(v.w);
  *(uint2*)(out + (size_t)idx * 4) = *(uint2*)tmp;
}

// ------------------------------ pos table ----------------------------------
__global__ void pe_kernel(float* __restrict__ pe) {
  int k = blockIdx.x * blockDim.x + threadIdx.x;
  if (k >= 512) return;
  float freq = expf(-(2.0f * (float)k / 1024.0f) * logf(10000.0f));
  pe[2 * k]          = 0.0f;          // pos 0: sin(0)
  pe[2 * k + 1]      = 1.0f;          // pos 0: cos(0)
  pe[1024 + 2 * k]     = sinf(freq);  // pos 1
  pe[1024 + 2 * k + 1] = cosf(freq);
}

// ------------------------------ GEMM (B^T) ---------------------------------
// C[m][n] = sum_k A[m][k] * Bw[n][k].  A,Bw bf16 row-major.
// MODE 0: write C f32 row-major.
// MODE 1: QKV scatter: n<1024 -> Q[b][h][i][dh]; n<2048 -> K same; else V^T
template <int MODE>
__global__ __launch_bounds__(256)
void gemm_bt(const __hip_bfloat16* __restrict__ A,
             const __hip_bfloat16* __restrict__ Bw,
             float* __restrict__ C,
             __hip_bfloat16* __restrict__ Qb,
             __hip_bfloat16* __restrict__ Kb,
             __hip_bfloat16* __restrict__ VTb,
             int Ndim, int Kdim) {
  constexpr int BK = 64;
  __shared__ __hip_bfloat16 sA[128 * BK];
  __shared__ __hip_bfloat16 sB[128 * BK];
  const int t = threadIdx.x, w = t >> 6, l = t & 63;
  const int bm = blockIdx.y * 128, bn = blockIdx.x * 128;
  const int m0 = (w >> 1) * 64, n0 = (w & 1) * 64;
  const int lrow = l >> 3, lcol = l & 7;
  const int ll = l & 15, lg = l >> 4;

  f32x4 acc[4][4] = {};

  for (int kt = 0; kt < Kdim; kt += BK) {
    __syncthreads();
#pragma unroll
    for (int r = 0; r < 4; ++r) {
      const int chunk = r * 4 + w;
      const int row = chunk * 8 + lrow;
      gload16((char*)sA + chunk * 1024 + l * 16,
              A + (size_t)(bm + row) * Kdim + kt + lcol * 8);
      gload16((char*)sB + chunk * 1024 + l * 16,
              Bw + (size_t)(bn + row) * Kdim + kt + lcol * 8);
    }
    __syncthreads();
#pragma unroll
    for (int ks = 0; ks < 2; ++ks) {
      bf16x8 a[4], b[4];
#pragma unroll
      for (int mi = 0; mi < 4; ++mi)
        a[mi] = *(const bf16x8*)((const char*)sA +
                 (m0 + mi * 16 + ll) * 128 + ks * 64 + lg * 16);
#pragma unroll
      for (int ni = 0; ni < 4; ++ni)
        b[ni] = *(const bf16x8*)((const char*)sB +
                 (n0 + ni * 16 + ll) * 128 + ks * 64 + lg * 16);
#pragma unroll
      for (int mi = 0; mi < 4; ++mi)
#pragma unroll
        for (int ni = 0; ni < 4; ++ni)
          acc[mi][ni] = __builtin_amdgcn_mfma_f32_16x16x32_bf16(
              a[mi], b[ni], acc[mi][ni], 0, 0, 0);
    }
  }

#pragma unroll
  for (int mi = 0; mi < 4; ++mi)
#pragma unroll
    for (int ni = 0; ni < 4; ++ni)
#pragma unroll
      for (int r = 0; r < 4; ++r) {
        const int gm = bm + m0 + mi * 16 + lg * 4 + r;
        const int gn = bn + n0 + ni * 16 + ll;
        const float v = acc[mi][ni][r];
        if (MODE == 0) {
          C[(size_t)gm * Ndim + gn] = v;
        } else {
          const int i = gm >> 1, bb = gm & 1;
          const __hip_bfloat16 hv = __float2bfloat16(v);
          if (gn < 1024) {
            const int h = gn >> 6, dh = gn & 63;
            Qb[(((size_t)(bb * 16 + h)) * 2048 + i) * 64 + dh] = hv;
          } else if (gn < 2048) {
            const int e = gn - 1024, h = e >> 6, dh = e & 63;
            Kb[(((size_t)(bb * 16 + h)) * 2048 + i) * 64 + dh] = hv;
          } else {
            const int e = gn - 2048, h = e >> 6, dh = e & 63;
            VTb[(((size_t)(bb * 16 + h)) * 64 + dh) * 2048 + i] = hv;
          }
        }
      }
}

// ----------------------------- flash attention ------------------------------
// 2-pass, swapped QK^T.  grid.x = q-tile (32 tiles of 64 rows), grid.y = bh.
// 4 waves/block, each wave owns 16 q rows and the full kv range.
// Pass 1: S = mfma(K,Q) -> in-lane running fmax (scores for q = ll).
// Pass 2: p = exp2(s*C1 - mm); in-lane row-sum; P routed via padded LDS row
//         (2x ds_write_b64, 2x ds_read 8B) into PV A-frag; PV vs V^T.
__global__ __launch_bounds__(256)
void attn_kernel(const __hip_bfloat16* __restrict__ Qb,
                 const __hip_bfloat16* __restrict__ Kb,
                 const __hip_bfloat16* __restrict__ VTb,
                 __hip_bfloat16* __restrict__ vec) {
  __shared__ __align__(16) __hip_bfloat16 pl[4][16 * 36];  // 72B-padded rows
  const int t = threadIdx.x, w = t >> 6, l = t & 63;
  const int qt = blockIdx.x, bh = blockIdx.y;
  const int b = bh >> 4, h = bh & 15;
  const __hip_bfloat16* Q  = Qb + (size_t)bh * S_SEQ * DH;
  const __hip_bfloat16* K  = Kb + (size_t)bh * S_SEQ * DH;
  const __hip_bfloat16* VT = VTb + (size_t)bh * DH * S_SEQ;
  const int ll = l & 15, lg = l >> 4;
  constexpr float C1 = 0.125f * 1.44269504088896f;  // scale * log2(e)

  const int qrow = qt * 64 + w * 16 + ll;
  const bf16x8 qf0 = *(const bf16x8*)(Q + (size_t)qrow * 64 + lg * 8);
  const bf16x8 qf1 = *(const bf16x8*)(Q + (size_t)qrow * 64 + 32 + lg * 8);

  // ---- pass 1: exact per-row max (row q = ll), no cross-lane ops in loop --
  float rm = -1e30f;
  for (int j0 = 0; j0 < S_SEQ; j0 += 32) {
    bf16x8 k00 = *(const bf16x8*)(K + (size_t)(j0 + ll) * 64 + lg * 8);
    bf16x8 k01 = *(const bf16x8*)(K + (size_t)(j0 + ll) * 64 + 32 + lg * 8);
    bf16x8 k10 = *(const bf16x8*)(K + (size_t)(j0 + 16 + ll) * 64 + lg * 8);
    bf16x8 k11 = *(const bf16x8*)(K + (size_t)(j0 + 16 + ll) * 64 + 32 + lg * 8);
    f32x4 s0 = {0.f, 0.f, 0.f, 0.f}, s1 = {0.f, 0.f, 0.f, 0.f};
    s0 = __builtin_amdgcn_mfma_f32_16x16x32_bf16(k00, qf0, s0, 0, 0, 0);
    s0 = __builtin_amdgcn_mfma_f32_16x16x32_bf16(k01, qf1, s0, 0, 0, 0);
    s1 = __builtin_amdgcn_mfma_f32_16x16x32_bf16(k10, qf0, s1, 0, 0, 0);
    s1 = __builtin_amdgcn_mfma_f32_16x16x32_bf16(k11, qf1, s1, 0, 0, 0);
#pragma unroll
    for (int r = 0; r < 4; ++r) rm = fmaxf(rm, fmaxf(s0[r], s1[r]));
  }
  rm = fmaxf(rm, __shfl_xor(rm, 16));
  rm = fmaxf(rm, __shfl_xor(rm, 32));
  const float mm = rm * C1;   // exp2-domain subtractor for row q = ll

  // ---- pass 2: exp + PV accumulate, no rescaling ---------------------------
  float lsum = 0.f;
  f32x4 oacc[4] = {};
  char* rowp = (char*)pl[w] + ll * 72;

  for (int j0 = 0; j0 < S_SEQ; j0 += 32) {
    bf16x8 k00 = *(const bf16x8*)(K + (size_t)(j0 + ll) * 64 + lg * 8);
    bf16x8 k01 = *(const bf16x8*)(K + (size_t)(j0 + ll) * 64 + 32 + lg * 8);
    bf16x8 k10 = *(const bf16x8*)(K + (size_t)(j0 + 16 + ll) * 64 + lg * 8);
    bf16x8 k11 = *(const bf16x8*)(K + (size_t)(j0 + 16 + ll) * 64 + 32 + lg * 8);
    f32x4 s0 = {0.f, 0.f, 0.f, 0.f}, s1 = {0.f, 0.f, 0.f, 0.f};
    s0 = __builtin_amdgcn_mfma_f32_16x16x32_bf16(k00, qf0, s0, 0, 0, 0);
    s0 = __builtin_amdgcn_mfma_f32_16x16x32_bf16(k01, qf1, s0, 0, 0, 0);
    s1 = __builtin_amdgcn_mfma_f32_16x16x32_bf16(k10, qf0, s1, 0, 0, 0);
    s1 = __builtin_amdgcn_mfma_f32_16x16x32_bf16(k11, qf1, s1, 0, 0, 0);

    // p = exp2(s*C1 - mm); scores in s0 = kv 4lg+r, s1 = kv 16+4lg+r, q = ll
    float p0[4], p1[4];
#pragma unroll
    for (int r = 0; r < 4; ++r) {
      p0[r] = exp2f(fmaf(s0[r], C1, -mm));
      p1[r] = exp2f(fmaf(s1[r], C1, -mm));
    }
    lsum += (p0[0] + p0[1]) + (p0[2] + p0[3]) +
            (p1[0] + p1[1]) + (p1[2] + p1[3]);

    // pack to bf16 and route through padded LDS row (q = ll)
    union { __hip_bfloat16 hx[8]; uint2 u2[2]; } pk_;
#pragma unroll
    for (int r = 0; r < 4; ++r) {
      pk_.hx[r]     = __float2bfloat16(p0[r]);
      pk_.hx[4 + r] = __float2bfloat16(p1[r]);
    }
    *(uint2*)(rowp + lg * 8)      = pk_.u2[0];   // kv 4lg..4lg+3
    *(uint2*)(rowp + 32 + lg * 8) = pk_.u2[1];   // kv 16+4lg..+3

    union { uint2 u2[2]; bf16x8 v; } pa;         // A-frag: P[q=ll][kv=lg*8+j]
    pa.u2[0] = *(const uint2*)(rowp + lg * 16);
    pa.u2[1] = *(const uint2*)(rowp + lg * 16 + 8);

#pragma unroll
    for (int df = 0; df < 4; ++df) {
      bf16x8 vf = *(const bf16x8*)(VT + (size_t)(df * 16 + ll) * S_SEQ + j0 + lg * 8);
      oacc[df] = __builtin_amdgcn_mfma_f32_16x16x32_bf16(pa.v, vf, oacc[df], 0, 0, 0);
    }
  }

  // ---- epilogue: one reduce, redistribute inv-sum to C-layout rows --------
  lsum += __shfl_xor(lsum, 16);
  lsum += __shfl_xor(lsum, 32);
  const float inv = 1.0f / lsum;      // for row q = ll
  float invr[4];
#pragma unroll
  for (int r = 0; r < 4; ++r) invr[r] = __shfl(inv, lg * 4 + r);

  const int i0 = qt * 64 + w * 16;
#pragma unroll
  for (int df = 0; df < 4; ++df)
#pragma unroll
    for (int r = 0; r < 4; ++r) {
      const int row = i0 + lg * 4 + r;          // C-layout: q = lg*4+r
      const int e = h * 64 + df * 16 + ll;      // dh = df*16+ll
      vec[((size_t)row * 2 + b) * 1024 + e] =
          __float2bfloat16(oacc[df][r] * invr[r]);
    }
}

// --------------------- residual add + LayerNorm (fused) ---------------------
__global__ __launch_bounds__(256)
void add_ln_kernel(const float* __restrict__ X, const float* __restrict__ Yadd,
                   const float* __restrict__ g, const float* __restrict__ bb,
                   float* __restrict__ out_f32,
                   __hip_bfloat16* __restrict__ out_b16) {
  const int row = blockIdx.x, t = threadIdx.x;
  const float4 x4 = *(const float4*)(X + (size_t)row * 1024 + t * 4);
  const float4 a4 = *(const float4*)(Yadd + (size_t)row * 1024 + t * 4);
  float v[4] = {x4.x + a4.x, x4.y + a4.y, x4.z + a4.z, x4.w + a4.w};
  float s = v[0] + v[1] + v[2] + v[3];
  float s2 = v[0] * v[0] + v[1] * v[1] + v[2] * v[2] + v[3] * v[3];
#pragma unroll
  for (int off = 1; off < 64; off <<= 1) {
    s += __shfl_xor(s, off);
    s2 += __shfl_xor(s2, off);
  }
  __shared__ float rs[4], rs2[4];
  if ((t & 63) == 0) { rs[t >> 6] = s; rs2[t >> 6] = s2; }
  __syncthreads();
  const float tot = rs[0] + rs[1] + rs[2] + rs[3];
  const float tot2 = rs2[0] + rs2[1] + rs2[2] + rs2[3];
  const float mu = tot * (1.0f / 1024.0f);
  const float var = tot2 * (1.0f / 1024.0f) - mu * mu;
  const float rstd = rsqrtf(var + 1e-5f);
  const float4 g4 = *(const float4*)(g + t * 4);
  const float4 b4 = *(const float4*)(bb + t * 4);
  float y[4];
  y[0] = (v[0] - mu) * rstd * g4.x + b4.x;
  y[1] = (v[1] - mu) * rstd * g4.y + b4.y;
  y[2] = (v[2] - mu) * rstd * g4.z + b4.z;
  y[3] = (v[3] - mu) * rstd * g4.w + b4.w;
  *(float4*)(out_f32 + (size_t)row * 1024 + t * 4) =
      make_float4(y[0], y[1], y[2], y[3]);
  __hip_bfloat16 tmp[4] = {__float2bfloat16(y[0]), __float2bfloat16(y[1]),
                           __float2bfloat16(y[2]), __float2bfloat16(y[3])};
  *(uint2*)(out_b16 + (size_t)row * 1024 + t * 4) = *(uint2*)tmp;
}

// ---------------- residual add + LayerNorm + 2*y + pe (final) ---------------
__global__ __launch_bounds__(256)
void final_kernel(const float* __restrict__ X, const float* __restrict__ Yadd,
                  const float* __restrict__ g, const float* __restrict__ bb,
                  const float* __restrict__ pe, float* __restrict__ out) {
  const int row = blockIdx.x, t = threadIdx.x;
  const float4 x4 = *(const float4*)(X + (size_t)row * 1024 + t * 4);
  const float4 a4 = *(const float4*)(Yadd + (size_t)row * 1024 + t * 4);
  float v[4] = {x4.x + a4.x, x4.y + a4.y, x4.z + a4.z, x4.w + a4.w};
  float s = v[0] + v[1] + v[2] + v[3];
  float s2 = v[0] * v[0] + v[1] * v[1] + v[2] * v[2] + v[3] * v[3];
#pragma unroll
  for (int off = 1; off < 64; off <<= 1) {
    s += __shfl_xor(s, off);
    s2 += __shfl_xor(s2, off);
  }
  __shared__ float rs[4], rs2[4];
  if ((t & 63) == 0) { rs[t >> 6] = s; rs2[t >> 6] = s2; }
  __syncthreads();
  const float tot = rs[0] + rs[1] + rs[2] + rs[3];
  const float tot2 = rs2[0] + rs2[1] + rs2[2] + rs2[3];
  const float mu = tot * (1.0f / 1024.0f);
  const float var = tot2 * (1.0f / 1024.0f) - mu * mu;
  const float rstd = rsqrtf(var + 1e-5f);
  const float4 g4 = *(const float4*)(g + t * 4);
  const float4 b4 = *(const float4*)(bb + t * 4);
  const int bidx = row & 1;
  const float4 p4 = *(const float4*)(pe + bidx * 1024 + t * 4);
  float y[4];
  y[0] = 2.0f * ((v[0] - mu) * rstd * g4.x + b4.x) + p4.x;
  y[1] = 2.0f * ((v[1] - mu) * rstd * g4.y + b4.y) + p4.y;
  y[2] = 2.0f * ((v[2] - mu) * rstd * g4.z + b4.z) + p4.z;
  y[3] = 2.0f * ((v[3] - mu) * rstd * g4.w + b4.w) + p4.w;
  *(float4*)(out + (size_t)row * 1024 + t * 4) = make_float4(y[0], y[1], y[2], y[3]);
}

// ---------------------------------------------------------------------------
extern "C" void kernel_launch(void* const* d_in, const int* in_sizes, int n_in,
                              void* d_out, int out_size, void* d_ws,
                              size_t ws_size, hipStream_t stream) {
  const float* x   = (const float*)d_in[0];
  const float* Wq  = (const float*)d_in[1];
  const float* Wkv = (const float*)d_in[2];
  const float* Wo  = (const float*)d_in[3];
  const float* g1  = (const float*)d_in[4];
  const float* b1  = (const float*)d_in[5];
  const float* Wff = (const float*)d_in[6];
  const float* g2  = (const float*)d_in[7];
  const float* b2  = (const float*)d_in[8];

  char* ws = (char*)d_ws;
  __hip_bfloat16* Wqkv_b = (__hip_bfloat16*)(ws + 0);          // 6 MB
  __hip_bfloat16* Wo_b   = (__hip_bfloat16*)(ws + 6 * WS_MB);  // 2 MB
  __hip_bfloat16* Wff_b  = (__hip_bfloat16*)(ws + 8 * WS_MB);  // 2 MB
  __hip_bfloat16* Xb     = (__hip_bfloat16*)(ws + 10 * WS_MB); // 8 MB
  __hip_bfloat16* Qb     = (__hip_bfloat16*)(ws + 18 * WS_MB); // 8 MB
  __hip_bfloat16* Kb     = (__hip_bfloat16*)(ws + 26 * WS_MB); // 8 MB
  __hip_bfloat16* VTb    = (__hip_bfloat16*)(ws + 34 * WS_MB); // 8 MB
  __hip_bfloat16* vecb   = (__hip_bfloat16*)(ws + 42 * WS_MB); // 8 MB
  float* attn            = (float*)(ws + 18 * WS_MB);          // 16 MB (alias Q+K)
  float* out1            = (float*)(ws + 50 * WS_MB);          // 16 MB
  __hip_bfloat16* out1b  = (__hip_bfloat16*)(ws + 66 * WS_MB); // 8 MB
  float* ffb             = (float*)(ws + 34 * WS_MB);          // 16 MB (alias VT+vec)
  float* pe              = (float*)(ws + 74 * WS_MB);          // 8 KB

  cvt_f32_bf16<<<4096, 256, 0, stream>>>(x, Xb, 1048576);
  cvt_f32_bf16<<<1024, 256, 0, stream>>>(Wq, Wqkv_b, 262144);
  cvt_f32_bf16<<<2048, 256, 0, stream>>>(Wkv, Wqkv_b + 1024 * 1024, 524288);
  cvt_f32_bf16<<<1024, 256, 0, stream>>>(Wo, Wo_b, 262144);
  cvt_f32_bf16<<<1024, 256, 0, stream>>>(Wff, Wff_b, 262144);
  pe_kernel<<<1, 512, 0, stream>>>(pe);

  gemm_bt<1><<<dim3(24, 32), 256, 0, stream>>>(Xb, Wqkv_b, nullptr, Qb, Kb, VTb,
                                               3072, 1024);
  attn_kernel<<<dim3(32, 32), 256, 0, stream>>>(Qb, Kb, VTb, vecb);
  gemm_bt<0><<<dim3(8, 32), 256, 0, stream>>>(vecb, Wo_b, attn, nullptr, nullptr,
                                              nullptr, 1024, 1024);
  add_ln_kernel<<<4096, 256, 0, stream>>>(x, attn, g1, b1, out1, out1b);
  gemm_bt<0><<<dim3(8, 32), 256, 0, stream>>>(out1b, Wff_b, ffb, nullptr, nullptr,
                                              nullptr, 1024, 1024);
  final_kernel<<<4096, 256, 0, stream>>>(out1, ffb, g2, b2, pe, (float*)d_out);
}

// Round 3
// 275.979 us; speedup vs baseline: 1.7953x; 1.7953x over previous
//
#include <hip/hip_runtime.h>
#include <hip/hip_bf16.h>
#include <math.h>

// ---------------------------------------------------------------------------
// UpdateAttn: decoder block = QKV proj -> MHA (no mask) -> Wo + res + LN1
//             -> Wff + res + LN2 -> 2*out + pos_emb(batch)
// S=2048 B=2 D=1024 H=16 DH=64.  All GEMMs bf16 MFMA; residual/LN in f32.
// R2: single-pass online softmax w/ defer-max; permuted-K rows so the PV
//     A-fragment materializes in-register (no LDS, no shuffles, no 2nd pass).
// ---------------------------------------------------------------------------

typedef __bf16 bf16x8 __attribute__((ext_vector_type(8)));
typedef float f32x4  __attribute__((ext_vector_type(4)));

typedef const __attribute__((address_space(1))) unsigned int as1_uint;
typedef __attribute__((address_space(3))) unsigned int as3_uint;

constexpr int S_SEQ = 2048;
constexpr int DH    = 64;

#define WS_MB (1ull << 20)

__device__ __forceinline__ void gload16(void* lds, const void* g) {
  __builtin_amdgcn_global_load_lds((as1_uint*)g, (as3_uint*)lds, 16, 0, 0);
}

// -------------------------- f32 -> bf16 convert ----------------------------
__global__ void cvt_f32_bf16(const float* __restrict__ in,
                             __hip_bfloat16* __restrict__ out, int n4) {
  int idx = blockIdx.x * blockDim.x + threadIdx.x;
  if (idx >= n4) return;
  float4 v = ((const float4*)in)[idx];
  __hip_bfloat16 tmp[4];
  tmp[0] = __float2bfloat16(v.x);
  tmp[1] = __float2bfloat16(v.y);
  tmp[2] = __float2bfloat16(v.z);
  tmp[3] = __float2bfloat16(v.w);
  *(uint2*)(out + (size_t)idx * 4) = *(uint2*)tmp;
}

// ------------------------------ pos table ----------------------------------
__global__ void pe_kernel(float* __restrict__ pe) {
  int k = blockIdx.x * blockDim.x + threadIdx.x;
  if (k >= 512) return;
  float freq = expf(-(2.0f * (float)k / 1024.0f) * logf(10000.0f));
  pe[2 * k]          = 0.0f;          // pos 0: sin(0)
  pe[2 * k + 1]      = 1.0f;          // pos 0: cos(0)
  pe[1024 + 2 * k]     = sinf(freq);  // pos 1
  pe[1024 + 2 * k + 1] = cosf(freq);
}

// ------------------------------ GEMM (B^T) ---------------------------------
template <int MODE>
__global__ __launch_bounds__(256)
void gemm_bt(const __hip_bfloat16* __restrict__ A,
             const __hip_bfloat16* __restrict__ Bw,
             float* __restrict__ C,
             __hip_bfloat16* __restrict__ Qb,
             __hip_bfloat16* __restrict__ Kb,
             __hip_bfloat16* __restrict__ VTb,
             int Ndim, int Kdim) {
  constexpr int BK = 64;
  __shared__ __hip_bfloat16 sA[128 * BK];
  __shared__ __hip_bfloat16 sB[128 * BK];
  const int t = threadIdx.x, w = t >> 6, l = t & 63;
  const int bm = blockIdx.y * 128, bn = blockIdx.x * 128;
  const int m0 = (w >> 1) * 64, n0 = (w & 1) * 64;
  const int lrow = l >> 3, lcol = l & 7;
  const int ll = l & 15, lg = l >> 4;

  f32x4 acc[4][4] = {};

  for (int kt = 0; kt < Kdim; kt += BK) {
    __syncthreads();
#pragma unroll
    for (int r = 0; r < 4; ++r) {
      const int chunk = r * 4 + w;
      const int row = chunk * 8 + lrow;
      gload16((char*)sA + chunk * 1024 + l * 16,
              A + (size_t)(bm + row) * Kdim + kt + lcol * 8);
      gload16((char*)sB + chunk * 1024 + l * 16,
              Bw + (size_t)(bn + row) * Kdim + kt + lcol * 8);
    }
    __syncthreads();
#pragma unroll
    for (int ks = 0; ks < 2; ++ks) {
      bf16x8 a[4], b[4];
#pragma unroll
      for (int mi = 0; mi < 4; ++mi)
        a[mi] = *(const bf16x8*)((const char*)sA +
                 (m0 + mi * 16 + ll) * 128 + ks * 64 + lg * 16);
#pragma unroll
      for (int ni = 0; ni < 4; ++ni)
        b[ni] = *(const bf16x8*)((const char*)sB +
                 (n0 + ni * 16 + ll) * 128 + ks * 64 + lg * 16);
#pragma unroll
      for (int mi = 0; mi < 4; ++mi)
#pragma unroll
        for (int ni = 0; ni < 4; ++ni)
          acc[mi][ni] = __builtin_amdgcn_mfma_f32_16x16x32_bf16(
              a[mi], b[ni], acc[mi][ni], 0, 0, 0);
    }
  }

#pragma unroll
  for (int mi = 0; mi < 4; ++mi)
#pragma unroll
    for (int ni = 0; ni < 4; ++ni)
#pragma unroll
      for (int r = 0; r < 4; ++r) {
        const int gm = bm + m0 + mi * 16 + lg * 4 + r;
        const int gn = bn + n0 + ni * 16 + ll;
        const float v = acc[mi][ni][r];
        if (MODE == 0) {
          C[(size_t)gm * Ndim + gn] = v;
        } else {
          const int i = gm >> 1, bb = gm & 1;
          const __hip_bfloat16 hv = __float2bfloat16(v);
          if (gn < 1024) {
            const int h = gn >> 6, dh = gn & 63;
            Qb[(((size_t)(bb * 16 + h)) * 2048 + i) * 64 + dh] = hv;
          } else if (gn < 2048) {
            const int e = gn - 1024, h = e >> 6, dh = e & 63;
            Kb[(((size_t)(bb * 16 + h)) * 2048 + i) * 64 + dh] = hv;
          } else {
            const int e = gn - 2048, h = e >> 6, dh = e & 63;
            VTb[(((size_t)(bb * 16 + h)) * 64 + dh) * 2048 + i] = hv;
          }
        }
      }
}

// ----------------------------- flash attention ------------------------------
// Single pass, online softmax with defer-max (THR = 8 nats).
// grid = (16 q-tiles of 128, 32 bh); 4 waves/block; wave owns 32 q-rows (qi=0,1).
// Swapped QK^T with PERMUTED K rows: MFMA-0 loads K row 8*(ll>>2)+(ll&3),
// MFMA-1 row +4.  Result: lane(ll,lg) holds scores for q=qi*16+ll,
// kv = j0+8lg..j0+8lg+7 -- exactly the PV A-fragment after exp+pack.
__global__ __launch_bounds__(256)
void attn_kernel(const __hip_bfloat16* __restrict__ Qb,
                 const __hip_bfloat16* __restrict__ Kb,
                 const __hip_bfloat16* __restrict__ VTb,
                 __hip_bfloat16* __restrict__ vec) {
  const int t = threadIdx.x, w = t >> 6, l = t & 63;
  const int qt = blockIdx.x, bh = blockIdx.y;
  const int b = bh >> 4, h = bh & 15;
  const __hip_bfloat16* Q  = Qb + (size_t)bh * S_SEQ * DH;
  const __hip_bfloat16* K  = Kb + (size_t)bh * S_SEQ * DH;
  const __hip_bfloat16* VT = VTb + (size_t)bh * DH * S_SEQ;
  const int ll = l & 15, lg = l >> 4;
  constexpr float C1   = 0.125f * 1.44269504088896f;  // scale * log2(e)
  constexpr float THR2 = 11.5416f;                    // 8 nats in exp2 domain

  const int qbase = qt * 128 + w * 32;
  bf16x8 qf[2][2];
#pragma unroll
  for (int qi = 0; qi < 2; ++qi) {
    qf[qi][0] = *(const bf16x8*)(Q + (size_t)(qbase + qi * 16 + ll) * 64 + lg * 8);
    qf[qi][1] = *(const bf16x8*)(Q + (size_t)(qbase + qi * 16 + ll) * 64 + 32 + lg * 8);
  }
  const int pr0 = 8 * (ll >> 2) + (ll & 3);   // permuted K row for MFMA-0

  float mm[2]   = {-1e30f, -1e30f};
  float lsum[2] = {0.f, 0.f};
  f32x4 oacc[2][4] = {};

  for (int j0 = 0; j0 < S_SEQ; j0 += 32) {
    __syncthreads();   // keep 4 waves converged -> L1 reuse of shared K/V tiles
    const __hip_bfloat16* Kj = K + (size_t)j0 * 64;
    bf16x8 k00 = *(const bf16x8*)(Kj + pr0 * 64 + lg * 8);
    bf16x8 k01 = *(const bf16x8*)(Kj + pr0 * 64 + 32 + lg * 8);
    bf16x8 k10 = *(const bf16x8*)(Kj + (pr0 + 4) * 64 + lg * 8);
    bf16x8 k11 = *(const bf16x8*)(Kj + (pr0 + 4) * 64 + 32 + lg * 8);
    bf16x8 vf[4];
#pragma unroll
    for (int df = 0; df < 4; ++df)
      vf[df] = *(const bf16x8*)(VT + (size_t)(df * 16 + ll) * S_SEQ + j0 + lg * 8);

    // QK^T: s0[qi][r] = score[kv=j0+8lg+r][q=qi*16+ll], s1 -> kv=j0+8lg+4+r
    f32x4 s0[2], s1[2];
#pragma unroll
    for (int qi = 0; qi < 2; ++qi) {
      f32x4 z = {0.f, 0.f, 0.f, 0.f};
      s0[qi] = __builtin_amdgcn_mfma_f32_16x16x32_bf16(k00, qf[qi][0], z, 0, 0, 0);
      s0[qi] = __builtin_amdgcn_mfma_f32_16x16x32_bf16(k01, qf[qi][1], s0[qi], 0, 0, 0);
      s1[qi] = __builtin_amdgcn_mfma_f32_16x16x32_bf16(k10, qf[qi][0], z, 0, 0, 0);
      s1[qi] = __builtin_amdgcn_mfma_f32_16x16x32_bf16(k11, qf[qi][1], s1[qi], 0, 0, 0);
    }

    // per-q tile max (exp2 domain)
    float pm[2];
#pragma unroll
    for (int qi = 0; qi < 2; ++qi) {
      float a = fmaxf(fmaxf(s0[qi][0], s0[qi][1]), fmaxf(s0[qi][2], s0[qi][3]));
      float c = fmaxf(fmaxf(s1[qi][0], s1[qi][1]), fmaxf(s1[qi][2], s1[qi][3]));
      float m = fmaxf(a, c) * C1;
      m = fmaxf(m, __shfl_xor(m, 16));
      m = fmaxf(m, __shfl_xor(m, 32));
      pm[qi] = m;
    }

    // defer-max: rescale only when some row grew past THR
    if (__any((pm[0] > mm[0] + THR2) || (pm[1] > mm[1] + THR2))) {
#pragma unroll
      for (int qi = 0; qi < 2; ++qi) {
        const float nm = fmaxf(mm[qi], pm[qi]);
        const float al = exp2f(mm[qi] - nm);
        mm[qi] = nm;
        lsum[qi] *= al;
        float aR[4];
#pragma unroll
        for (int r = 0; r < 4; ++r) aR[r] = __shfl(al, 4 * lg + r);
#pragma unroll
        for (int df = 0; df < 4; ++df)
#pragma unroll
          for (int r = 0; r < 4; ++r) oacc[qi][df][r] *= aR[r];
      }
    }

    // exp + pack (P stays in registers as the PV A-frag) + PV
#pragma unroll
    for (int qi = 0; qi < 2; ++qi) {
      float p[8];
#pragma unroll
      for (int r = 0; r < 4; ++r) {
        p[r]     = exp2f(fmaf(s0[qi][r], C1, -mm[qi]));
        p[4 + r] = exp2f(fmaf(s1[qi][r], C1, -mm[qi]));
      }
      lsum[qi] += ((p[0] + p[1]) + (p[2] + p[3])) +
                  ((p[4] + p[5]) + (p[6] + p[7]));
      union { __hip_bfloat16 hx[8]; bf16x8 v; } pk;
#pragma unroll
      for (int j = 0; j < 8; ++j) pk.hx[j] = __float2bfloat16(p[j]);
#pragma unroll
      for (int df = 0; df < 4; ++df)
        oacc[qi][df] = __builtin_amdgcn_mfma_f32_16x16x32_bf16(
            pk.v, vf[df], oacc[qi][df], 0, 0, 0);
    }
  }

  // epilogue: reduce row-sums, normalize, write
#pragma unroll
  for (int qi = 0; qi < 2; ++qi) {
    float ls = lsum[qi];
    ls += __shfl_xor(ls, 16);
    ls += __shfl_xor(ls, 32);
    const float inv = 1.0f / ls;          // for q = qi*16 + ll
    float invR[4];
#pragma unroll
    for (int r = 0; r < 4; ++r) invR[r] = __shfl(inv, 4 * lg + r);
#pragma unroll
    for (int df = 0; df < 4; ++df)
#pragma unroll
      for (int r = 0; r < 4; ++r) {
        const int row = qbase + qi * 16 + 4 * lg + r;
        const int e = h * 64 + df * 16 + ll;
        vec[((size_t)row * 2 + b) * 1024 + e] =
            __float2bfloat16(oacc[qi][df][r] * invR[r]);
      }
  }
}

// --------------------- residual add + LayerNorm (fused) ---------------------
__global__ __launch_bounds__(256)
void add_ln_kernel(const float* __restrict__ X, const float* __restrict__ Yadd,
                   const float* __restrict__ g, const float* __restrict__ bb,
                   float* __restrict__ out_f32,
                   __hip_bfloat16* __restrict__ out_b16) {
  const int row = blockIdx.x, t = threadIdx.x;
  const float4 x4 = *(const float4*)(X + (size_t)row * 1024 + t * 4);
  const float4 a4 = *(const float4*)(Yadd + (size_t)row * 1024 + t * 4);
  float v[4] = {x4.x + a4.x, x4.y + a4.y, x4.z + a4.z, x4.w + a4.w};
  float s = v[0] + v[1] + v[2] + v[3];
  float s2 = v[0] * v[0] + v[1] * v[1] + v[2] * v[2] + v[3] * v[3];
#pragma unroll
  for (int off = 1; off < 64; off <<= 1) {
    s += __shfl_xor(s, off);
    s2 += __shfl_xor(s2, off);
  }
  __shared__ float rs[4], rs2[4];
  if ((t & 63) == 0) { rs[t >> 6] = s; rs2[t >> 6] = s2; }
  __syncthreads();
  const float tot = rs[0] + rs[1] + rs[2] + rs[3];
  const float tot2 = rs2[0] + rs2[1] + rs2[2] + rs2[3];
  const float mu = tot * (1.0f / 1024.0f);
  const float var = tot2 * (1.0f / 1024.0f) - mu * mu;
  const float rstd = rsqrtf(var + 1e-5f);
  const float4 g4 = *(const float4*)(g + t * 4);
  const float4 b4 = *(const float4*)(bb + t * 4);
  float y[4];
  y[0] = (v[0] - mu) * rstd * g4.x + b4.x;
  y[1] = (v[1] - mu) * rstd * g4.y + b4.y;
  y[2] = (v[2] - mu) * rstd * g4.z + b4.z;
  y[3] = (v[3] - mu) * rstd * g4.w + b4.w;
  *(float4*)(out_f32 + (size_t)row * 1024 + t * 4) =
      make_float4(y[0], y[1], y[2], y[3]);
  __hip_bfloat16 tmp[4] = {__float2bfloat16(y[0]), __float2bfloat16(y[1]),
                           __float2bfloat16(y[2]), __float2bfloat16(y[3])};
  *(uint2*)(out_b16 + (size_t)row * 1024 + t * 4) = *(uint2*)tmp;
}

// ---------------- residual add + LayerNorm + 2*y + pe (final) ---------------
__global__ __launch_bounds__(256)
void final_kernel(const float* __restrict__ X, const float* __restrict__ Yadd,
                  const float* __restrict__ g, const float* __restrict__ bb,
                  const float* __restrict__ pe, float* __restrict__ out) {
  const int row = blockIdx.x, t = threadIdx.x;
  const float4 x4 = *(const float4*)(X + (size_t)row * 1024 + t * 4);
  const float4 a4 = *(const float4*)(Yadd + (size_t)row * 1024 + t * 4);
  float v[4] = {x4.x + a4.x, x4.y + a4.y, x4.z + a4.z, x4.w + a4.w};
  float s = v[0] + v[1] + v[2] + v[3];
  float s2 = v[0] * v[0] + v[1] * v[1] + v[2] * v[2] + v[3] * v[3];
#pragma unroll
  for (int off = 1; off < 64; off <<= 1) {
    s += __shfl_xor(s, off);
    s2 += __shfl_xor(s2, off);
  }
  __shared__ float rs[4], rs2[4];
  if ((t & 63) == 0) { rs[t >> 6] = s; rs2[t >> 6] = s2; }
  __syncthreads();
  const float tot = rs[0] + rs[1] + rs[2] + rs[3];
  const float tot2 = rs2[0] + rs2[1] + rs2[2] + rs2[3];
  const float mu = tot * (1.0f / 1024.0f);
  const float var = tot2 * (1.0f / 1024.0f) - mu * mu;
  const float rstd = rsqrtf(var + 1e-5f);
  const float4 g4 = *(const float4*)(g + t * 4);
  const float4 b4 = *(const float4*)(bb + t * 4);
  const int bidx = row & 1;
  const float4 p4 = *(const float4*)(pe + bidx * 1024 + t * 4);
  float y[4];
  y[0] = 2.0f * ((v[0] - mu) * rstd * g4.x + b4.x) + p4.x;
  y[1] = 2.0f * ((v[1] - mu) * rstd * g4.y + b4.y) + p4.y;
  y[2] = 2.0f * ((v[2] - mu) * rstd * g4.z + b4.z) + p4.z;
  y[3] = 2.0f * ((v[3] - mu) * rstd * g4.w + b4.w) + p4.w;
  *(float4*)(out + (size_t)row * 1024 + t * 4) = make_float4(y[0], y[1], y[2], y[3]);
}

// ---------------------------------------------------------------------------
extern "C" void kernel_launch(void* const* d_in, const int* in_sizes, int n_in,
                              void* d_out, int out_size, void* d_ws,
                              size_t ws_size, hipStream_t stream) {
  const float* x   = (const float*)d_in[0];
  const float* Wq  = (const float*)d_in[1];
  const float* Wkv = (const float*)d_in[2];
  const float* Wo  = (const float*)d_in[3];
  const float* g1  = (const float*)d_in[4];
  const float* b1  = (const float*)d_in[5];
  const float* Wff = (const float*)d_in[6];
  const float* g2  = (const float*)d_in[7];
  const float* b2  = (const float*)d_in[8];

  char* ws = (char*)d_ws;
  __hip_bfloat16* Wqkv_b = (__hip_bfloat16*)(ws + 0);          // 6 MB
  __hip_bfloat16* Wo_b   = (__hip_bfloat16*)(ws + 6 * WS_MB);  // 2 MB
  __hip_bfloat16* Wff_b  = (__hip_bfloat16*)(ws + 8 * WS_MB);  // 2 MB
  __hip_bfloat16* Xb     = (__hip_bfloat16*)(ws + 10 * WS_MB); // 8 MB
  __hip_bfloat16* Qb     = (__hip_bfloat16*)(ws + 18 * WS_MB); // 8 MB
  __hip_bfloat16* Kb     = (__hip_bfloat16*)(ws + 26 * WS_MB); // 8 MB
  __hip_bfloat16* VTb    = (__hip_bfloat16*)(ws + 34 * WS_MB); // 8 MB
  __hip_bfloat16* vecb   = (__hip_bfloat16*)(ws + 42 * WS_MB); // 8 MB
  float* attn            = (float*)(ws + 18 * WS_MB);          // 16 MB (alias Q+K)
  float* out1            = (float*)(ws + 50 * WS_MB);          // 16 MB
  __hip_bfloat16* out1b  = (__hip_bfloat16*)(ws + 66 * WS_MB); // 8 MB
  float* ffb             = (float*)(ws + 34 * WS_MB);          // 16 MB (alias VT+vec)
  float* pe              = (float*)(ws + 74 * WS_MB);          // 8 KB

  cvt_f32_bf16<<<4096, 256, 0, stream>>>(x, Xb, 1048576);
  cvt_f32_bf16<<<1024, 256, 0, stream>>>(Wq, Wqkv_b, 262144);
  cvt_f32_bf16<<<2048, 256, 0, stream>>>(Wkv, Wqkv_b + 1024 * 1024, 524288);
  cvt_f32_bf16<<<1024, 256, 0, stream>>>(Wo, Wo_b, 262144);
  cvt_f32_bf16<<<1024, 256, 0, stream>>>(Wff, Wff_b, 262144);
  pe_kernel<<<1, 512, 0, stream>>>(pe);

  gemm_bt<1><<<dim3(24, 32), 256, 0, stream>>>(Xb, Wqkv_b, nullptr, Qb, Kb, VTb,
                                               3072, 1024);
  attn_kernel<<<dim3(16, 32), 256, 0, stream>>>(Qb, Kb, VTb, vecb);
  gemm_bt<0><<<dim3(8, 32), 256, 0, stream>>>(vecb, Wo_b, attn, nullptr, nullptr,
                                              nullptr, 1024, 1024);
  add_ln_kernel<<<4096, 256, 0, stream>>>(x, attn, g1, b1, out1, out1b);
  gemm_bt<0><<<dim3(8, 32), 256, 0, stream>>>(out1b, Wff_b, ffb, nullptr, nullptr,
                                              nullptr, 1024, 1024);
  final_kernel<<<4096, 256, 0, stream>>>(out1, ffb, g2, b2, pe, (float*)d_out);
}

// Round 4
// 274.508 us; speedup vs baseline: 1.8049x; 1.0054x over previous
//
#include <hip/hip_runtime.h>
#include <hip/hip_bf16.h>
#include <math.h>

// ---------------------------------------------------------------------------
// UpdateAttn: decoder block = QKV proj -> MHA (no mask) -> Wo + res + LN1
//             -> Wff + res + LN2 -> 2*out + pos_emb(batch)
// S=2048 B=2 D=1024 H=16 DH=64.  All GEMMs bf16 MFMA; residual/LN in f32.
// R3: attn gets (1) XCD-grouped block swizzle so each XCD's L2 holds its 4
//     bh's K/V (2 MB) resident, (2) 1-deep register double-buffer prefetch of
//     K/V fragments so L2 latency hides under MFMA+VALU of the current tile.
// ---------------------------------------------------------------------------

typedef __bf16 bf16x8 __attribute__((ext_vector_type(8)));
typedef float f32x4  __attribute__((ext_vector_type(4)));

typedef const __attribute__((address_space(1))) unsigned int as1_uint;
typedef __attribute__((address_space(3))) unsigned int as3_uint;

constexpr int S_SEQ = 2048;
constexpr int DH    = 64;

#define WS_MB (1ull << 20)

__device__ __forceinline__ void gload16(void* lds, const void* g) {
  __builtin_amdgcn_global_load_lds((as1_uint*)g, (as3_uint*)lds, 16, 0, 0);
}

// -------------------------- f32 -> bf16 convert ----------------------------
__global__ void cvt_f32_bf16(const float* __restrict__ in,
                             __hip_bfloat16* __restrict__ out, int n4) {
  int idx = blockIdx.x * blockDim.x + threadIdx.x;
  if (idx >= n4) return;
  float4 v = ((const float4*)in)[idx];
  __hip_bfloat16 tmp[4];
  tmp[0] = __float2bfloat16(v.x);
  tmp[1] = __float2bfloat16(v.y);
  tmp[2] = __float2bfloat16(v.z);
  tmp[3] = __float2bfloat16(v.w);
  *(uint2*)(out + (size_t)idx * 4) = *(uint2*)tmp;
}

// ------------------------------ pos table ----------------------------------
__global__ void pe_kernel(float* __restrict__ pe) {
  int k = blockIdx.x * blockDim.x + threadIdx.x;
  if (k >= 512) return;
  float freq = expf(-(2.0f * (float)k / 1024.0f) * logf(10000.0f));
  pe[2 * k]          = 0.0f;          // pos 0: sin(0)
  pe[2 * k + 1]      = 1.0f;          // pos 0: cos(0)
  pe[1024 + 2 * k]     = sinf(freq);  // pos 1
  pe[1024 + 2 * k + 1] = cosf(freq);
}

// ------------------------------ GEMM (B^T) ---------------------------------
template <int MODE>
__global__ __launch_bounds__(256)
void gemm_bt(const __hip_bfloat16* __restrict__ A,
             const __hip_bfloat16* __restrict__ Bw,
             float* __restrict__ C,
             __hip_bfloat16* __restrict__ Qb,
             __hip_bfloat16* __restrict__ Kb,
             __hip_bfloat16* __restrict__ VTb,
             int Ndim, int Kdim) {
  constexpr int BK = 64;
  __shared__ __hip_bfloat16 sA[128 * BK];
  __shared__ __hip_bfloat16 sB[128 * BK];
  const int t = threadIdx.x, w = t >> 6, l = t & 63;
  const int bm = blockIdx.y * 128, bn = blockIdx.x * 128;
  const int m0 = (w >> 1) * 64, n0 = (w & 1) * 64;
  const int lrow = l >> 3, lcol = l & 7;
  const int ll = l & 15, lg = l >> 4;

  f32x4 acc[4][4] = {};

  for (int kt = 0; kt < Kdim; kt += BK) {
    __syncthreads();
#pragma unroll
    for (int r = 0; r < 4; ++r) {
      const int chunk = r * 4 + w;
      const int row = chunk * 8 + lrow;
      gload16((char*)sA + chunk * 1024 + l * 16,
              A + (size_t)(bm + row) * Kdim + kt + lcol * 8);
      gload16((char*)sB + chunk * 1024 + l * 16,
              Bw + (size_t)(bn + row) * Kdim + kt + lcol * 8);
    }
    __syncthreads();
#pragma unroll
    for (int ks = 0; ks < 2; ++ks) {
      bf16x8 a[4], b[4];
#pragma unroll
      for (int mi = 0; mi < 4; ++mi)
        a[mi] = *(const bf16x8*)((const char*)sA +
                 (m0 + mi * 16 + ll) * 128 + ks * 64 + lg * 16);
#pragma unroll
      for (int ni = 0; ni < 4; ++ni)
        b[ni] = *(const bf16x8*)((const char*)sB +
                 (n0 + ni * 16 + ll) * 128 + ks * 64 + lg * 16);
#pragma unroll
      for (int mi = 0; mi < 4; ++mi)
#pragma unroll
        for (int ni = 0; ni < 4; ++ni)
          acc[mi][ni] = __builtin_amdgcn_mfma_f32_16x16x32_bf16(
              a[mi], b[ni], acc[mi][ni], 0, 0, 0);
    }
  }

#pragma unroll
  for (int mi = 0; mi < 4; ++mi)
#pragma unroll
    for (int ni = 0; ni < 4; ++ni)
#pragma unroll
      for (int r = 0; r < 4; ++r) {
        const int gm = bm + m0 + mi * 16 + lg * 4 + r;
        const int gn = bn + n0 + ni * 16 + ll;
        const float v = acc[mi][ni][r];
        if (MODE == 0) {
          C[(size_t)gm * Ndim + gn] = v;
        } else {
          const int i = gm >> 1, bb = gm & 1;
          const __hip_bfloat16 hv = __float2bfloat16(v);
          if (gn < 1024) {
            const int h = gn >> 6, dh = gn & 63;
            Qb[(((size_t)(bb * 16 + h)) * 2048 + i) * 64 + dh] = hv;
          } else if (gn < 2048) {
            const int e = gn - 1024, h = e >> 6, dh = e & 63;
            Kb[(((size_t)(bb * 16 + h)) * 2048 + i) * 64 + dh] = hv;
          } else {
            const int e = gn - 2048, h = e >> 6, dh = e & 63;
            VTb[(((size_t)(bb * 16 + h)) * 64 + dh) * 2048 + i] = hv;
          }
        }
      }
}

// ----------------------------- flash attention ------------------------------
// Single pass, online softmax with defer-max; permuted-K rows give the PV
// A-fragment in-register.  512 blocks (1D), XCD-grouped: xcd = bid&7 owns a
// fixed group of 4 bh -> that XCD's L2 holds 2 MB of K/V resident.
// K/V fragments double-buffered in registers (prefetch 1 tile ahead).

#define LOADKV(kk, vv, jj)                                                    \
  {                                                                           \
    const __hip_bfloat16* Kj = K + (size_t)(jj) * 64;                         \
    kk[0] = *(const bf16x8*)(Kj + pr0 * 64 + lg * 8);                         \
    kk[1] = *(const bf16x8*)(Kj + pr0 * 64 + 32 + lg * 8);                    \
    kk[2] = *(const bf16x8*)(Kj + (pr0 + 4) * 64 + lg * 8);                   \
    kk[3] = *(const bf16x8*)(Kj + (pr0 + 4) * 64 + 32 + lg * 8);              \
    _Pragma("unroll")                                                         \
    for (int df = 0; df < 4; ++df)                                            \
      vv[df] = *(const bf16x8*)(VT + (size_t)(df * 16 + ll) * S_SEQ + (jj) +  \
                                lg * 8);                                      \
  }

#define COMPUTE(kk, vv)                                                       \
  {                                                                           \
    f32x4 s0[2], s1[2];                                                       \
    _Pragma("unroll")                                                         \
    for (int qi = 0; qi < 2; ++qi) {                                          \
      f32x4 z = {0.f, 0.f, 0.f, 0.f};                                         \
      s0[qi] = __builtin_amdgcn_mfma_f32_16x16x32_bf16(kk[0], qf[qi][0], z, 0, 0, 0); \
      s0[qi] = __builtin_amdgcn_mfma_f32_16x16x32_bf16(kk[1], qf[qi][1], s0[qi], 0, 0, 0); \
      s1[qi] = __builtin_amdgcn_mfma_f32_16x16x32_bf16(kk[2], qf[qi][0], z, 0, 0, 0); \
      s1[qi] = __builtin_amdgcn_mfma_f32_16x16x32_bf16(kk[3], qf[qi][1], s1[qi], 0, 0, 0); \
    }                                                                         \
    float pm[2];                                                              \
    _Pragma("unroll")                                                         \
    for (int qi = 0; qi < 2; ++qi) {                                          \
      float a = fmaxf(fmaxf(s0[qi][0], s0[qi][1]), fmaxf(s0[qi][2], s0[qi][3])); \
      float c = fmaxf(fmaxf(s1[qi][0], s1[qi][1]), fmaxf(s1[qi][2], s1[qi][3])); \
      float m = fmaxf(a, c) * C1;                                             \
      m = fmaxf(m, __shfl_xor(m, 16));                                        \
      m = fmaxf(m, __shfl_xor(m, 32));                                        \
      pm[qi] = m;                                                             \
    }                                                                         \
    if (__any((pm[0] > mm[0] + THR2) || (pm[1] > mm[1] + THR2))) {            \
      _Pragma("unroll")                                                       \
      for (int qi = 0; qi < 2; ++qi) {                                        \
        const float nm = fmaxf(mm[qi], pm[qi]);                               \
        const float al = exp2f(mm[qi] - nm);                                  \
        mm[qi] = nm;                                                          \
        lsum[qi] *= al;                                                       \
        float aR[4];                                                          \
        _Pragma("unroll")                                                     \
        for (int r = 0; r < 4; ++r) aR[r] = __shfl(al, 4 * lg + r);           \
        _Pragma("unroll")                                                     \
        for (int df = 0; df < 4; ++df)                                        \
          _Pragma("unroll")                                                   \
          for (int r = 0; r < 4; ++r) oacc[qi][df][r] *= aR[r];               \
      }                                                                       \
    }                                                                         \
    _Pragma("unroll")                                                         \
    for (int qi = 0; qi < 2; ++qi) {                                          \
      float p[8];                                                             \
      _Pragma("unroll")                                                       \
      for (int r = 0; r < 4; ++r) {                                           \
        p[r]     = exp2f(fmaf(s0[qi][r], C1, -mm[qi]));                       \
        p[4 + r] = exp2f(fmaf(s1[qi][r], C1, -mm[qi]));                       \
      }                                                                       \
      lsum[qi] += ((p[0] + p[1]) + (p[2] + p[3])) +                           \
                  ((p[4] + p[5]) + (p[6] + p[7]));                            \
      union { __hip_bfloat16 hx[8]; bf16x8 v; } pk;                           \
      _Pragma("unroll")                                                       \
      for (int j = 0; j < 8; ++j) pk.hx[j] = __float2bfloat16(p[j]);          \
      _Pragma("unroll")                                                       \
      for (int df = 0; df < 4; ++df)                                          \
        oacc[qi][df] = __builtin_amdgcn_mfma_f32_16x16x32_bf16(               \
            pk.v, vv[df], oacc[qi][df], 0, 0, 0);                             \
    }                                                                         \
  }

__global__ __launch_bounds__(256)
void attn_kernel(const __hip_bfloat16* __restrict__ Qb,
                 const __hip_bfloat16* __restrict__ Kb,
                 const __hip_bfloat16* __restrict__ VTb,
                 __hip_bfloat16* __restrict__ vec) {
  const int t = threadIdx.x, w = t >> 6, l = t & 63;
  // XCD-grouped swizzle: 512 blocks; xcd = bid&7 (dispatch round-robin) gets
  // bh in a fixed group of 4, all 16 q-tiles -> K/V (2 MB) L2-resident.
  const int bid = blockIdx.x;
  const int slot = bid >> 3;
  const int bh = (bid & 7) * 4 + (slot & 3);
  const int qt = slot >> 2;                       // 0..15
  const int b = bh >> 4, h = bh & 15;
  const __hip_bfloat16* Q  = Qb + (size_t)bh * S_SEQ * DH;
  const __hip_bfloat16* K  = Kb + (size_t)bh * S_SEQ * DH;
  const __hip_bfloat16* VT = VTb + (size_t)bh * DH * S_SEQ;
  const int ll = l & 15, lg = l >> 4;
  constexpr float C1   = 0.125f * 1.44269504088896f;  // scale * log2(e)
  constexpr float THR2 = 11.5416f;                    // 8 nats in exp2 domain

  const int qbase = qt * 128 + w * 32;
  bf16x8 qf[2][2];
#pragma unroll
  for (int qi = 0; qi < 2; ++qi) {
    qf[qi][0] = *(const bf16x8*)(Q + (size_t)(qbase + qi * 16 + ll) * 64 + lg * 8);
    qf[qi][1] = *(const bf16x8*)(Q + (size_t)(qbase + qi * 16 + ll) * 64 + 32 + lg * 8);
  }
  const int pr0 = 8 * (ll >> 2) + (ll & 3);   // permuted K row for MFMA-0

  float mm[2]   = {-1e30f, -1e30f};
  float lsum[2] = {0.f, 0.f};
  f32x4 oacc[2][4] = {};

  bf16x8 ka[4], va[4], kb[4], vb[4];
  LOADKV(ka, va, 0);

  for (int j0 = 0; j0 < S_SEQ; j0 += 64) {
    __syncthreads();
    LOADKV(kb, vb, j0 + 32);                  // prefetch tile j0+32
    COMPUTE(ka, va);
    __syncthreads();
    {
      const int jn = (j0 + 64 < S_SEQ) ? j0 + 64 : 0;   // benign tail load
      LOADKV(ka, va, jn);                     // prefetch tile j0+64
    }
    COMPUTE(kb, vb);
  }

  // epilogue: reduce row-sums, normalize, write
#pragma unroll
  for (int qi = 0; qi < 2; ++qi) {
    float ls = lsum[qi];
    ls += __shfl_xor(ls, 16);
    ls += __shfl_xor(ls, 32);
    const float inv = 1.0f / ls;          // for q = qi*16 + ll
    float invR[4];
#pragma unroll
    for (int r = 0; r < 4; ++r) invR[r] = __shfl(inv, 4 * lg + r);
#pragma unroll
    for (int df = 0; df < 4; ++df)
#pragma unroll
      for (int r = 0; r < 4; ++r) {
        const int row = qbase + qi * 16 + 4 * lg + r;
        const int e = h * 64 + df * 16 + ll;
        vec[((size_t)row * 2 + b) * 1024 + e] =
            __float2bfloat16(oacc[qi][df][r] * invR[r]);
      }
  }
}

// --------------------- residual add + LayerNorm (fused) ---------------------
__global__ __launch_bounds__(256)
void add_ln_kernel(const float* __restrict__ X, const float* __restrict__ Yadd,
                   const float* __restrict__ g, const float* __restrict__ bb,
                   float* __restrict__ out_f32,
                   __hip_bfloat16* __restrict__ out_b16) {
  const int row = blockIdx.x, t = threadIdx.x;
  const float4 x4 = *(const float4*)(X + (size_t)row * 1024 + t * 4);
  const float4 a4 = *(const float4*)(Yadd + (size_t)row * 1024 + t * 4);
  float v[4] = {x4.x + a4.x, x4.y + a4.y, x4.z + a4.z, x4.w + a4.w};
  float s = v[0] + v[1] + v[2] + v[3];
  float s2 = v[0] * v[0] + v[1] * v[1] + v[2] * v[2] + v[3] * v[3];
#pragma unroll
  for (int off = 1; off < 64; off <<= 1) {
    s += __shfl_xor(s, off);
    s2 += __shfl_xor(s2, off);
  }
  __shared__ float rs[4], rs2[4];
  if ((t & 63) == 0) { rs[t >> 6] = s; rs2[t >> 6] = s2; }
  __syncthreads();
  const float tot = rs[0] + rs[1] + rs[2] + rs[3];
  const float tot2 = rs2[0] + rs2[1] + rs2[2] + rs2[3];
  const float mu = tot * (1.0f / 1024.0f);
  const float var = tot2 * (1.0f / 1024.0f) - mu * mu;
  const float rstd = rsqrtf(var + 1e-5f);
  const float4 g4 = *(const float4*)(g + t * 4);
  const float4 b4 = *(const float4*)(bb + t * 4);
  float y[4];
  y[0] = (v[0] - mu) * rstd * g4.x + b4.x;
  y[1] = (v[1] - mu) * rstd * g4.y + b4.y;
  y[2] = (v[2] - mu) * rstd * g4.z + b4.z;
  y[3] = (v[3] - mu) * rstd * g4.w + b4.w;
  *(float4*)(out_f32 + (size_t)row * 1024 + t * 4) =
      make_float4(y[0], y[1], y[2], y[3]);
  __hip_bfloat16 tmp[4] = {__float2bfloat16(y[0]), __float2bfloat16(y[1]),
                           __float2bfloat16(y[2]), __float2bfloat16(y[3])};
  *(uint2*)(out_b16 + (size_t)row * 1024 + t * 4) = *(uint2*)tmp;
}

// ---------------- residual add + LayerNorm + 2*y + pe (final) ---------------
__global__ __launch_bounds__(256)
void final_kernel(const float* __restrict__ X, const float* __restrict__ Yadd,
                  const float* __restrict__ g, const float* __restrict__ bb,
                  const float* __restrict__ pe, float* __restrict__ out) {
  const int row = blockIdx.x, t = threadIdx.x;
  const float4 x4 = *(const float4*)(X + (size_t)row * 1024 + t * 4);
  const float4 a4 = *(const float4*)(Yadd + (size_t)row * 1024 + t * 4);
  float v[4] = {x4.x + a4.x, x4.y + a4.y, x4.z + a4.z, x4.w + a4.w};
  float s = v[0] + v[1] + v[2] + v[3];
  float s2 = v[0] * v[0] + v[1] * v[1] + v[2] * v[2] + v[3] * v[3];
#pragma unroll
  for (int off = 1; off < 64; off <<= 1) {
    s += __shfl_xor(s, off);
    s2 += __shfl_xor(s2, off);
  }
  __shared__ float rs[4], rs2[4];
  if ((t & 63) == 0) { rs[t >> 6] = s; rs2[t >> 6] = s2; }
  __syncthreads();
  const float tot = rs[0] + rs[1] + rs[2] + rs[3];
  const float tot2 = rs2[0] + rs2[1] + rs2[2] + rs2[3];
  const float mu = tot * (1.0f / 1024.0f);
  const float var = tot2 * (1.0f / 1024.0f) - mu * mu;
  const float rstd = rsqrtf(var + 1e-5f);
  const float4 g4 = *(const float4*)(g + t * 4);
  const float4 b4 = *(const float4*)(bb + t * 4);
  const int bidx = row & 1;
  const float4 p4 = *(const float4*)(pe + bidx * 1024 + t * 4);
  float y[4];
  y[0] = 2.0f * ((v[0] - mu) * rstd * g4.x + b4.x) + p4.x;
  y[1] = 2.0f * ((v[1] - mu) * rstd * g4.y + b4.y) + p4.y;
  y[2] = 2.0f * ((v[2] - mu) * rstd * g4.z + b4.z) + p4.z;
  y[3] = 2.0f * ((v[3] - mu) * rstd * g4.w + b4.w) + p4.w;
  *(float4*)(out + (size_t)row * 1024 + t * 4) = make_float4(y[0], y[1], y[2], y[3]);
}

// ---------------------------------------------------------------------------
extern "C" void kernel_launch(void* const* d_in, const int* in_sizes, int n_in,
                              void* d_out, int out_size, void* d_ws,
                              size_t ws_size, hipStream_t stream) {
  const float* x   = (const float*)d_in[0];
  const float* Wq  = (const float*)d_in[1];
  const float* Wkv = (const float*)d_in[2];
  const float* Wo  = (const float*)d_in[3];
  const float* g1  = (const float*)d_in[4];
  const float* b1  = (const float*)d_in[5];
  const float* Wff = (const float*)d_in[6];
  const float* g2  = (const float*)d_in[7];
  const float* b2  = (const float*)d_in[8];

  char* ws = (char*)d_ws;
  __hip_bfloat16* Wqkv_b = (__hip_bfloat16*)(ws + 0);          // 6 MB
  __hip_bfloat16* Wo_b   = (__hip_bfloat16*)(ws + 6 * WS_MB);  // 2 MB
  __hip_bfloat16* Wff_b  = (__hip_bfloat16*)(ws + 8 * WS_MB);  // 2 MB
  __hip_bfloat16* Xb     = (__hip_bfloat16*)(ws + 10 * WS_MB); // 8 MB
  __hip_bfloat16* Qb     = (__hip_bfloat16*)(ws + 18 * WS_MB); // 8 MB
  __hip_bfloat16* Kb     = (__hip_bfloat16*)(ws + 26 * WS_MB); // 8 MB
  __hip_bfloat16* VTb    = (__hip_bfloat16*)(ws + 34 * WS_MB); // 8 MB
  __hip_bfloat16* vecb   = (__hip_bfloat16*)(ws + 42 * WS_MB); // 8 MB
  float* attn            = (float*)(ws + 18 * WS_MB);          // 16 MB (alias Q+K)
  float* out1            = (float*)(ws + 50 * WS_MB);          // 16 MB
  __hip_bfloat16* out1b  = (__hip_bfloat16*)(ws + 66 * WS_MB); // 8 MB
  float* ffb             = (float*)(ws + 34 * WS_MB);          // 16 MB (alias VT+vec)
  float* pe              = (float*)(ws + 74 * WS_MB);          // 8 KB

  cvt_f32_bf16<<<4096, 256, 0, stream>>>(x, Xb, 1048576);
  cvt_f32_bf16<<<1024, 256, 0, stream>>>(Wq, Wqkv_b, 262144);
  cvt_f32_bf16<<<2048, 256, 0, stream>>>(Wkv, Wqkv_b + 1024 * 1024, 524288);
  cvt_f32_bf16<<<1024, 256, 0, stream>>>(Wo, Wo_b, 262144);
  cvt_f32_bf16<<<1024, 256, 0, stream>>>(Wff, Wff_b, 262144);
  pe_kernel<<<1, 512, 0, stream>>>(pe);

  gemm_bt<1><<<dim3(24, 32), 256, 0, stream>>>(Xb, Wqkv_b, nullptr, Qb, Kb, VTb,
                                               3072, 1024);
  attn_kernel<<<dim3(512), 256, 0, stream>>>(Qb, Kb, VTb, vecb);
  gemm_bt<0><<<dim3(8, 32), 256, 0, stream>>>(vecb, Wo_b, attn, nullptr, nullptr,
                                              nullptr, 1024, 1024);
  add_ln_kernel<<<4096, 256, 0, stream>>>(x, attn, g1, b1, out1, out1b);
  gemm_bt<0><<<dim3(8, 32), 256, 0, stream>>>(out1b, Wff_b, ffb, nullptr, nullptr,
                                              nullptr, 1024, 1024);
  final_kernel<<<4096, 256, 0, stream>>>(out1, ffb, g2, b2, pe, (float*)d_out);
}